// Round 3
// baseline (357.309 us; speedup 1.0000x reference)
//
#include <hip/hip_runtime.h>
#include <stdint.h>

// B=512, T=256, N_EMBED=384, HEAD_SIZE=64
// Fully fused: one block per batch. QKV projected into LDS, attention runs
// entirely out of LDS. Only HBM traffic: x read (201 MB) + out write (33.5 MB).
// ws layout: [0, 147456) Wt2 bf16 [12 kc][192 n][32 kk] (n: 0..63=K, 64..127=Q(scaled), 128..191=V)

typedef short s16x8 __attribute__((ext_vector_type(8)));
typedef short s16x4 __attribute__((ext_vector_type(4)));
typedef float f32x4 __attribute__((ext_vector_type(4)));

#define LOG2E_OVER_8 0.18033688011112042f

__device__ inline short f2bf(float f) {
  union { float f; uint32_t u; } v; v.f = f;
  uint32_t r = (v.u + 0x7fffu + ((v.u >> 16) & 1u)) >> 16;  // RNE
  return (short)r;
}

// ---- Kernel 0: W fp32 [384][64] x3 -> bf16 Wt2[kc][n][kk], fold 0.125*log2e into Wq
__global__ __launch_bounds__(256) void prep_w(const float* __restrict__ Wk,
                                              const float* __restrict__ Wq,
                                              const float* __restrict__ Wv,
                                              short* __restrict__ Wt2) {
  int idx = blockIdx.x * 256 + threadIdx.x;  // 0..73727
  int kk = idx & 31;
  int n = (idx >> 5) % 192;
  int kc = idx / (32 * 192);
  int col = n & 63;
  int w = n >> 6;
  const float* W = (w == 0) ? Wk : (w == 1) ? Wq : Wv;
  float v = W[(kc * 32 + kk) * 64 + col];
  if (w == 1) v *= LOG2E_OVER_8;
  Wt2[idx] = f2bf(v);
}

// ---- Fused kernel: one block per batch, 512 threads (8 waves).
__global__ __launch_bounds__(512, 2) void fused_head(const float* __restrict__ x,
                                                     const short* __restrict__ Wt2,
                                                     float* __restrict__ out) {
  // LDS: 50176 + 36864 + 36864 + 33792 = 157696 B (<= 160 KiB/CU)
  __shared__ __align__(16) short Xs[64 * 392];    // proj staging; aliased by P-strips later
  __shared__ __align__(16) short Kls[256 * 72];   // K [s][h], stride 72
  __shared__ __align__(16) short Qls[256 * 72];   // Q [s][h] (pre-scaled), stride 72
  __shared__ __align__(16) short Vt[64 * 264];    // V^T [h][s], stride 264

  const int tid = threadIdx.x;
  const int wave = tid >> 6;
  const int lane = tid & 63;
  const int l15 = lane & 15;
  const int quad = lane >> 4;
  const int b = blockIdx.x;
  const float* xb = x + (long)b * (256 * 384);

  // ======== Phase 1: QKV projection into LDS ========
  const int rt = wave >> 1;  // row-tile within 64-row chunk (0..3)
  const int nh = wave & 1;   // col half: 0 -> n 0..95, 1 -> n 96..191
  const short* wbase = Wt2 + (nh * 96 + l15) * 32 + quad * 8;

  for (int ch = 0; ch < 4; ++ch) {
    const int R0 = ch * 64;
    // stage 64x384 fp32 -> bf16 into Xs: 64 rows x 96 f32x4 = 6144 slots, 512 thr x 12
#pragma unroll
    for (int j = 0; j < 12; ++j) {
      int slot = tid + j * 512;        // 0..6143
      int row = slot / 96;             // 96 f32x4 per row
      int c4 = slot - row * 96;
      f32x4 a = *(const f32x4*)(xb + (R0 + row) * 384 + c4 * 4);
      s16x4 h;
      h[0] = f2bf(a[0]); h[1] = f2bf(a[1]); h[2] = f2bf(a[2]); h[3] = f2bf(a[3]);
      *(s16x4*)&Xs[row * 392 + c4 * 4] = h;
    }
    __syncthreads();

    f32x4 acc[6];
#pragma unroll
    for (int nt = 0; nt < 6; ++nt) acc[nt] = (f32x4)0.0f;
    const short* abase = &Xs[(rt * 16 + l15) * 392 + quad * 8];
#pragma unroll 2
    for (int kc = 0; kc < 12; ++kc) {
      s16x8 af = *(const s16x8*)(abase + kc * 32);
#pragma unroll
      for (int nt = 0; nt < 6; ++nt) {
        s16x8 bf = *(const s16x8*)(wbase + kc * 6144 + nt * 512);
        acc[nt] = __builtin_amdgcn_mfma_f32_16x16x32_bf16(af, bf, acc[nt], 0, 0, 0);
      }
    }

    // epilogue: C layout col=l15, row=quad*4+r -> scatter to Kls/Qls/Vt
    const int srow = R0 + rt * 16 + quad * 4;
#pragma unroll
    for (int nt = 0; nt < 6; ++nt) {
      const int gn = nh * 6 + nt;  // global n-tile 0..11 (wave-uniform)
      if (gn < 4) {
        const int col = gn * 16 + l15;
#pragma unroll
        for (int r = 0; r < 4; ++r) Kls[(srow + r) * 72 + col] = f2bf(acc[nt][r]);
      } else if (gn < 8) {
        const int col = (gn - 4) * 16 + l15;
#pragma unroll
        for (int r = 0; r < 4; ++r) Qls[(srow + r) * 72 + col] = f2bf(acc[nt][r]);
      } else {
        const int hcol = (gn - 8) * 16 + l15;
#pragma unroll
        for (int r = 0; r < 4; ++r) Vt[hcol * 264 + srow + r] = f2bf(acc[nt][r]);
      }
    }
    __syncthreads();  // Xs reads + KQV writes complete before next chunk / attention
  }

  // ======== Phase 2: causal attention, all operands in LDS, no barriers ========
  short* Psw = Xs + wave * (16 * 72);  // wave-private P strip [16 t][72 s-stride]

  for (int ti = 0; ti < 2; ++ti) {
    const int t = ti ? (15 - wave) : wave;  // q-subtile 0..15, balanced: each wave 5 chunk-iters
    const int q0 = t * 16;

    s16x8 qf0 = *(const s16x8*)&Qls[(q0 + l15) * 72 + quad * 8];
    s16x8 qf1 = *(const s16x8*)&Qls[(q0 + l15) * 72 + 32 + quad * 8];

    f32x4 Oacc[4];
#pragma unroll
    for (int n = 0; n < 4; ++n) Oacc[n] = (f32x4)0.0f;
    float mrow[4] = {-1e30f, -1e30f, -1e30f, -1e30f};
    float lrow[4] = {0.f, 0.f, 0.f, 0.f};

    const int nchunks = (t >> 2) + 1;
    for (int c = 0; c < nchunks; ++c) {
      const int s0 = c * 64;
      // S = Q K^T (log2 units)
      f32x4 S[4];
#pragma unroll
      for (int n = 0; n < 4; ++n) {
        s16x8 kf0 = *(const s16x8*)&Kls[(s0 + n * 16 + l15) * 72 + quad * 8];
        s16x8 kf1 = *(const s16x8*)&Kls[(s0 + n * 16 + l15) * 72 + 32 + quad * 8];
        f32x4 z = (f32x4)0.0f;
        z = __builtin_amdgcn_mfma_f32_16x16x32_bf16(qf0, kf0, z, 0, 0, 0);
        z = __builtin_amdgcn_mfma_f32_16x16x32_bf16(qf1, kf1, z, 0, 0, 0);
        S[n] = z;
      }
      if (c == nchunks - 1) {  // diagonal chunk: mask s > q
#pragma unroll
        for (int n = 0; n < 4; ++n) {
          const int s_abs = s0 + n * 16 + l15;
#pragma unroll
          for (int r = 0; r < 4; ++r) {
            const int q_abs = q0 + quad * 4 + r;
            if (s_abs > q_abs) S[n][r] = -1e30f;
          }
        }
      }

      // online softmax (base-2); row r lives in the 16 lanes of this quad
      float alpha[4];
#pragma unroll
      for (int r = 0; r < 4; ++r) {
        float mx = fmaxf(fmaxf(S[0][r], S[1][r]), fmaxf(S[2][r], S[3][r]));
        mx = fmaxf(mx, __shfl_xor(mx, 1));
        mx = fmaxf(mx, __shfl_xor(mx, 2));
        mx = fmaxf(mx, __shfl_xor(mx, 4));
        mx = fmaxf(mx, __shfl_xor(mx, 8));
        float mnew = fmaxf(mrow[r], mx);
        alpha[r] = __builtin_amdgcn_exp2f(mrow[r] - mnew);
        mrow[r] = mnew;
      }
      float rs[4] = {0.f, 0.f, 0.f, 0.f};
#pragma unroll
      for (int n = 0; n < 4; ++n) {
#pragma unroll
        for (int r = 0; r < 4; ++r) {
          float p = __builtin_amdgcn_exp2f(S[n][r] - mrow[r]);  // masked -> 0
          rs[r] += p;
          Psw[(quad * 4 + r) * 72 + n * 16 + l15] = f2bf(p);
        }
      }
#pragma unroll
      for (int r = 0; r < 4; ++r) {
        float s = rs[r];
        s += __shfl_xor(s, 1);
        s += __shfl_xor(s, 2);
        s += __shfl_xor(s, 4);
        s += __shfl_xor(s, 8);
        lrow[r] = lrow[r] * alpha[r] + s;
#pragma unroll
        for (int n = 0; n < 4; ++n) Oacc[n][r] *= alpha[r];
      }
      // P strip is wave-private: drain DS writes before re-reading (no barrier)
      asm volatile("s_waitcnt lgkmcnt(0)" ::: "memory");

      // O += P V
      s16x8 pf0 = *(const s16x8*)&Psw[l15 * 72 + quad * 8];
      s16x8 pf1 = *(const s16x8*)&Psw[l15 * 72 + 32 + quad * 8];
#pragma unroll
      for (int n = 0; n < 4; ++n) {
        s16x8 vf0 = *(const s16x8*)&Vt[(n * 16 + l15) * 264 + s0 + quad * 8];
        s16x8 vf1 = *(const s16x8*)&Vt[(n * 16 + l15) * 264 + s0 + 32 + quad * 8];
        Oacc[n] = __builtin_amdgcn_mfma_f32_16x16x32_bf16(pf0, vf0, Oacc[n], 0, 0, 0);
        Oacc[n] = __builtin_amdgcn_mfma_f32_16x16x32_bf16(pf1, vf1, Oacc[n], 0, 0, 0);
      }
    }

    float inv[4];
#pragma unroll
    for (int r = 0; r < 4; ++r) inv[r] = 1.0f / lrow[r];
    float* ob = out + ((long)b * 256 + q0 + quad * 4) * 64;
#pragma unroll
    for (int n = 0; n < 4; ++n)
#pragma unroll
      for (int r = 0; r < 4; ++r)
        ob[r * 64 + n * 16 + l15] = Oacc[n][r] * inv[r];
  }
}

extern "C" void kernel_launch(void* const* d_in, const int* in_sizes, int n_in,
                              void* d_out, int out_size, void* d_ws, size_t ws_size,
                              hipStream_t stream) {
  const float* x = (const float*)d_in[0];
  const float* Wk = (const float*)d_in[1];
  const float* Wq = (const float*)d_in[2];
  const float* Wv = (const float*)d_in[3];
  float* out = (float*)d_out;
  short* Wt2 = (short*)d_ws;  // 147456 B

  prep_w<<<288, 256, 0, stream>>>(Wk, Wq, Wv, Wt2);
  fused_head<<<512, 512, 0, stream>>>(x, Wt2, out);
}

// Round 4
// 318.451 us; speedup vs baseline: 1.1220x; 1.1220x over previous
//
#include <hip/hip_runtime.h>
#include <stdint.h>

// B=512, T=256, N_EMBED=384, HEAD_SIZE=64
// One block per batch, 1024 threads (16 waves, 4/SIMD).
// Phase 1: kc-outer QKV projection; per-kc x-slice + W-slice staged in LDS
//          (fragment-ordered), register-prefetched; acc in AGPRs.
// Phase 2: causal flash attention, 128-wide s-chunks, all operands in LDS in
//          canonical MFMA fragment order (conflict-free ds_read_b128).
// LDS total = 163840 B (exactly 160 KiB): Kf 32K + Qf 32K + Vf 32K + P 64K
//             (P region aliases phase-1 staging: Xc 16K + Wsl 12K).
// ws: Wt3 bf16 fragment-ordered [12 kc][12 ntile][64 lane][8] = 147456 B
//     (ntile 0..3 = K, 4..7 = Q (prescaled by 0.125*log2e), 8..11 = V)

typedef short s16x8 __attribute__((ext_vector_type(8)));
typedef short s16x4 __attribute__((ext_vector_type(4)));
typedef float f32x4 __attribute__((ext_vector_type(4)));

#define LOG2E_OVER_8 0.18033688011112042f

__device__ inline short f2bf(float f) {
  union { float f; uint32_t u; } v; v.f = f;
  uint32_t r = (v.u + 0x7fffu + ((v.u >> 16) & 1u)) >> 16;  // RNE
  return (short)r;
}

// ---- Kernel 0: W fp32 -> bf16 fragment-ordered Wt3, fold 0.125*log2e into Wq
__global__ __launch_bounds__(256) void prep_w(const float* __restrict__ Wk,
                                              const float* __restrict__ Wq,
                                              const float* __restrict__ Wv,
                                              short* __restrict__ Wt3) {
  int idx = blockIdx.x * 256 + threadIdx.x;  // 0..73727
  int j = idx & 7;
  int lane = (idx >> 3) & 63;
  int rest = idx >> 9;          // 0..143
  int ntile = rest % 12;
  int kc = rest / 12;
  int n = ntile * 16 + (lane & 15);
  int kk = (lane >> 4) * 8 + j;
  int col = n & 63;
  int w = n >> 6;
  const float* W = (w == 0) ? Wk : (w == 1) ? Wq : Wv;
  float v = W[(kc * 32 + kk) * 64 + col];
  if (w == 1) v *= LOG2E_OVER_8;
  Wt3[idx] = f2bf(v);
}

// ---- Fused kernel: one block per batch, 1024 threads.
__global__ __launch_bounds__(1024) void fused_head(const float* __restrict__ x,
                                                   const short* __restrict__ Wt3,
                                                   float* __restrict__ out) {
  __shared__ __align__(16) short LDS[81920];  // 163840 B
  short* Kf = LDS;            // [stile16*2+frag][lane*8+j]  (B-frag: n=s, k=h)
  short* Qf = LDS + 16384;    // [qtile16*2+frag][lane*8+j]  (A-frag: m=q, k=h)
  short* Vf = LDS + 32768;    // [sblk32*4+htile][lane*8+j]  (B-frag: n=h, k=s)
  short* Pb = LDS + 49152;    // 16 waves x 2048 shorts: [sblk32][lane*8+j] (A-frag)
  short* Xc = LDS + 49152;    // phase-1 alias: [mtile16][lane*8+j] (A-frag, one kc)
  short* Wsl = LDS + 49152 + 8192;  // phase-1 alias: [ntile12][lane*8+j] (one kc)

  const int tid = threadIdx.x;
  const int wave = tid >> 6;
  const int lane = tid & 63;
  const int l15 = lane & 15;
  const int quad = lane >> 4;
  const int b = blockIdx.x;
  const float* xb = x + (long)b * (256 * 384);

  // ======== Phase 1: QKV projection (kc-outer, staged slices) ========
  const int mgrp = wave >> 2;  // 4 m-tiles (64 rows)
  const int ngrp = wave & 3;   // 3 n-tiles (48 cols)

  // x staging: slots 0..2047, slot = tid + j*1024; m=slot>>3, kq=(slot&7)*4
  const int m0s = tid >> 3;
  const int kq0 = (tid & 7) * 4;
  const int xoff0 = m0s * 384 + kq0;
  const int xoff1 = xoff0 + 128 * 384;
  const int lds0 = (m0s >> 4) * 512 + ((m0s & 15) + (kq0 >> 3) * 16) * 8 + (kq0 & 7);
  const int lds1 = lds0 + 8 * 512;
  const bool wact = (tid < 768);

  f32x4 acc[4][3];
#pragma unroll
  for (int i = 0; i < 4; ++i)
#pragma unroll
    for (int k2 = 0; k2 < 3; ++k2) acc[i][k2] = (f32x4)0.0f;

  f32x4 xa0 = *(const f32x4*)(xb + xoff0);
  f32x4 xa1 = *(const f32x4*)(xb + xoff1);
  s16x8 wv;
  if (wact) wv = *(const s16x8*)(Wt3 + tid * 8);

  for (int kc = 0; kc < 12; ++kc) {
    __syncthreads();  // previous MFMA reads done; staging area free
    s16x4 h0, h1;
    h0[0] = f2bf(xa0[0]); h0[1] = f2bf(xa0[1]); h0[2] = f2bf(xa0[2]); h0[3] = f2bf(xa0[3]);
    h1[0] = f2bf(xa1[0]); h1[1] = f2bf(xa1[1]); h1[2] = f2bf(xa1[2]); h1[3] = f2bf(xa1[3]);
    *(s16x4*)(Xc + lds0) = h0;
    *(s16x4*)(Xc + lds1) = h1;
    if (wact) *(s16x8*)(Wsl + tid * 8) = wv;
    __syncthreads();
    if (kc < 11) {  // prefetch kc+1 (overlaps MFMA below)
      xa0 = *(const f32x4*)(xb + xoff0 + (kc + 1) * 32);
      xa1 = *(const f32x4*)(xb + xoff1 + (kc + 1) * 32);
      if (wact) wv = *(const s16x8*)(Wt3 + (kc + 1) * 6144 + tid * 8);
    }
    s16x8 af[4];
#pragma unroll
    for (int i = 0; i < 4; ++i)
      af[i] = *(const s16x8*)(Xc + (mgrp * 4 + i) * 512 + lane * 8);
#pragma unroll
    for (int k2 = 0; k2 < 3; ++k2) {
      s16x8 bfv = *(const s16x8*)(Wsl + (ngrp * 3 + k2) * 512 + lane * 8);
#pragma unroll
      for (int i = 0; i < 4; ++i)
        acc[i][k2] = __builtin_amdgcn_mfma_f32_16x16x32_bf16(af[i], bfv, acc[i][k2], 0, 0, 0);
    }
  }

  // epilogue: C layout (row=quad*4+r, col=nt*16+l15) -> fragment-ordered K/Q/V
#pragma unroll
  for (int i = 0; i < 4; ++i) {
    const int rowb = (mgrp * 4 + i) * 16 + quad * 4;
#pragma unroll
    for (int k2 = 0; k2 < 3; ++k2) {
      const int nt = ngrp * 3 + k2;  // 0..11 (wave-uniform)
      const int h = (nt * 16 + l15) & 63;
      const int which = nt >> 2;
#pragma unroll
      for (int r = 0; r < 4; ++r) {
        const short v = f2bf(acc[i][k2][r]);
        const int row = rowb + r;
        if (which == 0)
          Kf[((row >> 4) * 2 + (h >> 5)) * 512 + ((row & 15) + ((h & 31) >> 3) * 16) * 8 + (h & 7)] = v;
        else if (which == 1)
          Qf[((row >> 4) * 2 + (h >> 5)) * 512 + ((row & 15) + ((h & 31) >> 3) * 16) * 8 + (h & 7)] = v;
        else
          Vf[((row >> 5) * 4 + (h >> 4)) * 512 + ((h & 15) + ((row & 31) >> 3) * 16) * 8 + (row & 7)] = v;
      }
    }
  }
  __syncthreads();  // K/Q/V complete; staging area (P region) free

  // ======== Phase 2: causal attention, wave w owns q-subtile w ========
  const int t = wave;
  const int q0 = t * 16;
  short* Pw = Pb + wave * 2048;

  s16x8 qf0 = *(const s16x8*)(Qf + (t * 2 + 0) * 512 + lane * 8);
  s16x8 qf1 = *(const s16x8*)(Qf + (t * 2 + 1) * 512 + lane * 8);

  f32x4 Oacc[4];
#pragma unroll
  for (int n = 0; n < 4; ++n) Oacc[n] = (f32x4)0.0f;
  float mrow[4] = {-1e30f, -1e30f, -1e30f, -1e30f};
  float lrow[4] = {0.f, 0.f, 0.f, 0.f};

  const int nb = (t >= 8) ? 2 : 1;
  for (int cb = 0; cb < nb; ++cb) {
    const int st0 = cb * 8;                       // first 16-s-tile of this 128-chunk
    const bool last = (cb == nb - 1);
    const int nuse = last ? (t - cb * 8 + 1) : 8; // tiles with any unmasked col

    float S[8][4];
#pragma unroll
    for (int n = 0; n < 8; ++n) {
      if (n < nuse) {
        s16x8 kf0 = *(const s16x8*)(Kf + ((st0 + n) * 2 + 0) * 512 + lane * 8);
        s16x8 kf1 = *(const s16x8*)(Kf + ((st0 + n) * 2 + 1) * 512 + lane * 8);
        f32x4 z = (f32x4)0.0f;
        z = __builtin_amdgcn_mfma_f32_16x16x32_bf16(qf0, kf0, z, 0, 0, 0);
        z = __builtin_amdgcn_mfma_f32_16x16x32_bf16(qf1, kf1, z, 0, 0, 0);
        if (last) {
          const int s_abs = cb * 128 + n * 16 + l15;
#pragma unroll
          for (int r = 0; r < 4; ++r) {
            const int q_abs = q0 + quad * 4 + r;
            S[n][r] = (s_abs > q_abs) ? -1e30f : z[r];
          }
        } else {
#pragma unroll
          for (int r = 0; r < 4; ++r) S[n][r] = z[r];
        }
      } else {
#pragma unroll
        for (int r = 0; r < 4; ++r) S[n][r] = -1e30f;
      }
    }

    // online softmax (base-2); row r lives in the 16 lanes of this quad
    float alpha[4];
#pragma unroll
    for (int r = 0; r < 4; ++r) {
      float mx = S[0][r];
#pragma unroll
      for (int n = 1; n < 8; ++n) mx = fmaxf(mx, S[n][r]);
      mx = fmaxf(mx, __shfl_xor(mx, 1));
      mx = fmaxf(mx, __shfl_xor(mx, 2));
      mx = fmaxf(mx, __shfl_xor(mx, 4));
      mx = fmaxf(mx, __shfl_xor(mx, 8));
      float mnew = fmaxf(mrow[r], mx);
      alpha[r] = __builtin_amdgcn_exp2f(mrow[r] - mnew);
      mrow[r] = mnew;
    }
    float rs[4] = {0.f, 0.f, 0.f, 0.f};
#pragma unroll
    for (int n = 0; n < 8; ++n) {
#pragma unroll
      for (int r = 0; r < 4; ++r) {
        float p = __builtin_amdgcn_exp2f(S[n][r] - mrow[r]);  // masked -> 0
        rs[r] += p;
        Pw[(n >> 1) * 512 + ((quad * 4 + r) + ((n & 1) * 2 + (l15 >> 3)) * 16) * 8 + (l15 & 7)] = f2bf(p);
      }
    }
#pragma unroll
    for (int r = 0; r < 4; ++r) {
      float s = rs[r];
      s += __shfl_xor(s, 1);
      s += __shfl_xor(s, 2);
      s += __shfl_xor(s, 4);
      s += __shfl_xor(s, 8);
      lrow[r] = lrow[r] * alpha[r] + s;
#pragma unroll
      for (int n = 0; n < 4; ++n) Oacc[n][r] *= alpha[r];
    }
    // P strip is wave-private: drain DS writes before re-reading (no barrier)
    asm volatile("s_waitcnt lgkmcnt(0)" ::: "memory");

    // O += P V over the live 32-s blocks
    const int kblks = (nuse + 1) >> 1;
    for (int sb = 0; sb < kblks; ++sb) {
      s16x8 pf = *(const s16x8*)(Pw + sb * 512 + lane * 8);
#pragma unroll
      for (int n2 = 0; n2 < 4; ++n2) {
        s16x8 vfv = *(const s16x8*)(Vf + ((cb * 4 + sb) * 4 + n2) * 512 + lane * 8);
        Oacc[n2] = __builtin_amdgcn_mfma_f32_16x16x32_bf16(pf, vfv, Oacc[n2], 0, 0, 0);
      }
    }
  }

  float inv[4];
#pragma unroll
  for (int r = 0; r < 4; ++r) inv[r] = 1.0f / lrow[r];
  float* ob = out + ((long)b * 256 + q0 + quad * 4) * 64;
#pragma unroll
  for (int n = 0; n < 4; ++n)
#pragma unroll
    for (int r = 0; r < 4; ++r)
      ob[r * 64 + n * 16 + l15] = Oacc[n][r] * inv[r];
}

extern "C" void kernel_launch(void* const* d_in, const int* in_sizes, int n_in,
                              void* d_out, int out_size, void* d_ws, size_t ws_size,
                              hipStream_t stream) {
  const float* x = (const float*)d_in[0];
  const float* Wk = (const float*)d_in[1];
  const float* Wq = (const float*)d_in[2];
  const float* Wv = (const float*)d_in[3];
  float* out = (float*)d_out;
  short* Wt3 = (short*)d_ws;  // 147456 B

  prep_w<<<288, 256, 0, stream>>>(Wk, Wq, Wv, Wt3);
  fused_head<<<512, 1024, 0, stream>>>(x, Wt3, out);
}